// Round 15
// baseline (446.819 us; speedup 1.0000x reference)
//
#include <hip/hip_runtime.h>

typedef unsigned short u16;
typedef unsigned int u32;
typedef unsigned long long u64;

#define B_TOTAL 65536
#define H 512
#define D 64
#define BM 128
#define CH 520   /* zbuf chunk stride in u16 (512 data + 8 pad: de-conflicts writes) */

typedef __bf16 bf16x8 __attribute__((ext_vector_type(8)));
typedef float f32x4 __attribute__((ext_vector_type(4)));
typedef float f32x16 __attribute__((ext_vector_type(16)));

__device__ __forceinline__ u32 f2b(float f) {  // fp32 -> bf16 bits, RNE (sw)
  u32 u = __builtin_bit_cast(u32, f);
  return (u + 0x7fffu + ((u >> 16) & 1u)) >> 16;
}
__device__ __forceinline__ u16 f2bc(float f) { // fp32 -> bf16 bits via HW cvt
  return __builtin_bit_cast(u16, (__bf16)f);
}
__device__ __forceinline__ float b2f(u32 bits) {
  return __builtin_bit_cast(float, bits << 16);
}

// ---- workspace layout (bf16 element offsets) ----
// Weight regions FRAGMENT-PACKED for 32x32x16 MFMA (verified in R14):
// packed[( (n>>5)*(KK/16) + (k>>4) )*512 + lane*8 + j] = M[n][k],
// n = ntile*32 + (lane&31), k = kstep*16 + (lane>>5)*8 + j.
#define OFF_Wz0b 0          /* [N=512][K=64]  fwd L0 */
#define OFF_Wx0b 32768
#define OFF_Wx1b 65536
#define OFF_Wx2b 98304
#define OFF_Wz1b 131072     /* [N=512][K=512] fwd */
#define OFF_Wz2b 393216
#define OFF_Wz3b 655360
#define OFF_Wz1t 917504     /* [N=512][K=512] transposed, bwd */
#define OFF_Wz2t 1179648
#define OFF_Wz3t 1441792
#define OFF_Wz0t 1703936    /* [N=64][K=512] transposed grad weights */
#define OFF_Wx0t 1736704
#define OFF_Wx1t 1769472
#define OFF_Wx2t 1802240
#define OFF_WEND 1835008
// Slabs return in R15 (sigmoid storage; frees 48 regs for BM=128's acc).
#define SLAB_ELEMS (B_TOTAL * H)          /* bf16-equivalents per slab */
#define OFF_S0 OFF_WEND
#define OFF_S1 (OFF_S0 + SLAB_ELEMS)
#define OFF_S2 (OFF_S1 + SLAB_ELEMS)
#define WS_ELEMS (OFF_S2 + SLAB_ELEMS)

// ---- weight prep: fp32 -> bf16, fragment-packed for 32x32x16 ----
__global__ __launch_bounds__(256) void prep_kernel(
    const float* __restrict__ Wz0, const float* __restrict__ Wz1,
    const float* __restrict__ Wz2, const float* __restrict__ Wz3,
    const float* __restrict__ Wx0, const float* __restrict__ Wx1,
    const float* __restrict__ Wx2, u16* __restrict__ wsb) {
  int i = blockIdx.x * 256 + threadIdx.x;   // grid exactly covers OFF_WEND
  const float* src;
  int NN, KK, trans, p;
  if (i < 131072) {                          // x-path fwd: [512][64] direct
    int r = i >> 15; p = i & 32767;
    src = (r == 0) ? Wz0 : (r == 1) ? Wx0 : (r == 2) ? Wx1 : Wx2;
    NN = 512; KK = 64; trans = 0;
  } else if (i < 917504) {                   // H fwd: [512][512] direct
    int j = i - 131072; int r = j >> 18; p = j & 262143;
    src = (r == 0) ? Wz1 : (r == 1) ? Wz2 : Wz3;
    NN = 512; KK = 512; trans = 0;
  } else if (i < 1703936) {                  // H bwd: transposed
    int j = i - 917504; int r = j >> 18; p = j & 262143;
    src = (r == 0) ? Wz1 : (r == 1) ? Wz2 : Wz3;
    NN = 512; KK = 512; trans = 1;
  } else {                                   // grad weights: [64][512] = W^T
    int j = i - 1703936; int r = j >> 15; p = j & 32767;
    src = (r == 0) ? Wz0 : (r == 1) ? Wx0 : (r == 2) ? Wx1 : Wx2;
    NN = 64; KK = 512; trans = 1;
  }
  int jj = p & 7, lane = (p >> 3) & 63, blk = p >> 9;
  int kt_sh = (KK == 64) ? 2 : 5;            // log2(KK/16)
  int ntile = blk >> kt_sh;
  int kstep = blk & ((1 << kt_sh) - 1);
  int n = ntile * 32 + (lane & 31);
  int k = kstep * 16 + ((lane >> 5) << 3) + jj;
  float v = trans ? src[k * NN + n] : src[n * KK + k];
  wsb[i] = (u16)f2b(v);
}

__global__ __launch_bounds__(256) void fill_sentinel(float* out, int n) {
  int i = blockIdx.x * 256 + threadIdx.x;
  if (i < n) out[i] = 12345.0f;   // unmistakable "workspace too small" marker
}

// ---- fully-fused ICNN fwd+bwd (single GEMM kernel) ----
// ROUND-15: BM=128 (512 blocks, 2 rounds/CU) to HALVE the L2 weight wall.
// R12 wall model (per CU): MFMA 110us | A-LDS ~122us | B-L2 ~110us (weights
// 3.7MB are L2-resident and re-read once PER BLOCK; R13 proved this wall is
// binding). BM=128 halves B-traffic per FLOP; A-LDS and MFMA per-FLOP
// unchanged. Enablers vs R4's failed BM=128:
//  - 32x32x16 frags (R14-verified layouts): wave w owns 128 rows x 32 cols
//    (ntile w) -> acc[4] x f32x16 = 64 regs; working set ~110-123 <= 128 cap;
//  - sigmoids back in GLOBAL SLABS (R9 proved the traffic is fully hidden)
//    -> no 48-reg sg array;
//  - B global->VGPR depth-2 rotation (R12-proven latency hiding).
// Single zbuf (no ping-pong; 133KB w/ CH=520 pad) -> per-layer WAR barrier
// returns (~16 lbars). minigrad: 8 out-tiles x 2 K-halves over 16 waves,
// one final LDS-park reduce (zbuf dead there). LDS = 133+18.4 = 151.5KB.
__global__ __launch_bounds__(1024, 4) void icnn_kernel(
    const float* __restrict__ state,
    const float* __restrict__ bz0, const float* __restrict__ bx0,
    const float* __restrict__ bx1, const float* __restrict__ bx2,
    const float* __restrict__ WzL, const float* __restrict__ WxL,
    u16* __restrict__ wsw, float* __restrict__ out) {
  __shared__ u16 zbuf[128 * CH];    // 32 ksteps x 4 rowtiles, 1KB chunks +pad
  __shared__ u16 xbuf[BM * 72];     // padded x staging, 18.4 KB

  const int tid = threadIdx.x;
  const int w = tid >> 6;           // 0..15
  const int lane = tid & 63;
  const int l31 = lane & 31;
  const int q5 = lane >> 5;
  const int blk = blockIdx.x;

  const u16* Wz0b = wsw + OFF_Wz0b;
  const u16* Wx0b = wsw + OFF_Wx0b;
  const u16* Wx1b = wsw + OFF_Wx1b;
  const u16* Wx2b = wsw + OFF_Wx2b;
  const u16* Wz1b = wsw + OFF_Wz1b;
  const u16* Wz2b = wsw + OFF_Wz2b;
  const u16* Wz3b = wsw + OFF_Wz3b;
  const u16* Wz1t = wsw + OFF_Wz1t;
  const u16* Wz2t = wsw + OFF_Wz2t;
  const u16* Wz3t = wsw + OFF_Wz3t;
  const u16* Wz0t = wsw + OFF_Wz0t;
  const u16* Wx0t = wsw + OFF_Wx0t;
  const u16* Wx1t = wsw + OFF_Wx1t;
  const u16* Wx2t = wsw + OFF_Wx2t;
  u64* slab0 = (u64*)(wsw + OFF_S0);
  u64* slab1 = (u64*)(wsw + OFF_S1);
  u64* slab2 = (u64*)(wsw + OFF_S2);

  auto lbar = [&]() {               // LDS-only barrier (no vmcnt drain)
    asm volatile("s_waitcnt lgkmcnt(0)" ::: "memory");
    __builtin_amdgcn_s_barrier();
    asm volatile("" ::: "memory");
  };

  // ---- stage x = state-1 into xbuf (bf16, padded row-major) ----
  {
#pragma unroll
    for (int ii = 0; ii < 2; ++ii) {
      int i = tid * 2 + ii;                  // 128 rows x 16 chunks of 4 floats
      int r = i >> 4, c0 = (i & 15) << 2;
      const float* p = state + (blk * BM + r) * D + c0;
      f32x4 v = __builtin_nontemporal_load((const f32x4*)p);
      u32* dst = (u32*)&xbuf[r * 72 + c0];
      dst[0] = (u32)f2bc(v[0] - 1.0f) | ((u32)f2bc(v[1] - 1.0f) << 16);
      dst[1] = (u32)f2bc(v[2] - 1.0f) | ((u32)f2bc(v[3] - 1.0f) << 16);
    }
  }

  const f32x16 Z16 = {0,0,0,0,0,0,0,0,0,0,0,0,0,0,0,0};
  f32x16 acc[4];                    // 4 rowtiles x 16 C-regs = 64 acc regs
  f32x16 pk = Z16;                  // grad partial: tile w&7, K-half w>>3

  // z[row][k] chunks: chunk(ks=k>>4, rt=row>>5) at (ks*4+rt)*CH; in-chunk
  // offset = (((k>>3)&1)*32 + (row&31))*8 + (k&7). A-frag read (rt,ks) is
  // one contiguous 1KB burst at chunk base + lane*8 (conflict-free).
  auto ldA = [&](int rt, int ks) -> bf16x8 {
    return *(const bf16x8*)(&zbuf[(ks * 4 + rt) * CH + lane * 8]);
  };
  auto ldX = [&](int rt, int ks) -> bf16x8 {   // x A-frag from padded xbuf
    return *(const bf16x8*)(&xbuf[(rt * 32 + l31) * 72 + ks * 16 + q5 * 8]);
  };

  // acc = x @ Wx^T (K=64), zero-start. Wx streams global->VGPR. ntile = w.
  auto fwdX = [&](const u16* Wxp) {
    const u16* xb = Wxp + (w * 4) * 512 + lane * 8;
#pragma unroll
    for (int ks = 0; ks < 4; ++ks) {
      bf16x8 b = *(const bf16x8*)(xb + ks * 512);
#pragma unroll
      for (int rt = 0; rt < 4; ++rt) {
        bf16x8 a = ldX(rt, ks);
        acc[rt] = __builtin_amdgcn_mfma_f32_32x32x16_bf16(
            a, b, (ks == 0) ? Z16 : acc[rt], 0, 0, 0);
      }
    }
  };

  // acc += zbuf @ W^T (K=512), ALWAYS accumulating. B streams global->VGPR,
  // depth-2 rotation (3 live frags = 12 regs); 32 ksteps of 16. 4 MFMA/step
  // = 4 independent chains (fixes R14's 2-chain dependency stall).
  auto fwdH = [&](const u16* Wp) {
    const u16* gb = Wp + (w * 32) * 512 + lane * 8;   // ntile = w
    bf16x8 b0 = *(const bf16x8*)(gb);
    bf16x8 b1 = *(const bf16x8*)(gb + 512);
#pragma unroll 2
    for (int st = 0; st < 32; ++st) {
      int stp = (st < 30) ? st + 2 : st;   // prefetch st+2 (clamped re-read)
      bf16x8 bn = *(const bf16x8*)(gb + stp * 512);
      bf16x8 a0 = ldA(0, st);
      bf16x8 a1 = ldA(1, st);
      bf16x8 a2 = ldA(2, st);
      bf16x8 a3 = ldA(3, st);
      __builtin_amdgcn_s_setprio(1);
      acc[0] = __builtin_amdgcn_mfma_f32_32x32x16_bf16(a0, b0, acc[0], 0, 0, 0);
      acc[1] = __builtin_amdgcn_mfma_f32_32x32x16_bf16(a1, b0, acc[1], 0, 0, 0);
      acc[2] = __builtin_amdgcn_mfma_f32_32x32x16_bf16(a2, b0, acc[2], 0, 0, 0);
      acc[3] = __builtin_amdgcn_mfma_f32_32x32x16_bf16(a3, b0, acc[3], 0, 0, 0);
      __builtin_amdgcn_s_setprio(0);
      b0 = b1; b1 = bn;
    }
  };
  auto zeroAcc = [&]() {
#pragma unroll
    for (int rt = 0; rt < 4; ++rt) acc[rt] = Z16;
  };

  // Per-lane constant base for epi scatter into zbuf:
  // col n = w*32+l31 -> chunk-col ks = w*2+(l31>>4); row = rt*32+e+8g+4q5.
  const int C0 = (w * 2 + (l31 >> 4)) * 4 * CH + ((l31 >> 3) & 1) * 256 +
                 q5 * 32 + (l31 & 7);

  // forward epilogue: a+=bias; z=softplus -> zbuf; s=sigmoid -> slab
  auto fwd_epi = [&](const float* biasp, u64* slab) {
    float bias = biasp[w * 32 + l31];
#pragma unroll
    for (int rt = 0; rt < 4; ++rt)
#pragma unroll
      for (int g = 0; g < 4; ++g) {
        u64 pack = 0;
#pragma unroll
        for (int e = 0; e < 4; ++e) {
          float a = acc[rt][g * 4 + e] + bias;
          float t = __expf(-a);
          float u = 1.0f + t;
          float s = __builtin_amdgcn_rcpf(u);     // sigmoid(a)
          float z = a + __logf(u);                // softplus(a)
          pack |= (u64)f2bc(s) << (16 * e);
          zbuf[C0 + rt * CH + (e + 8 * g) * 8] = f2bc(z);
        }
        slab[((blk * 16 + w) * 16 + rt * 4 + g) * 64 + lane] = pack;
      }
  };
  auto d3_epi = [&](const float* biasp) {   // d3 = WzL*sigmoid(a3) -> zbuf
    float bias = biasp[w * 32 + l31];
    float wl = WzL[w * 32 + l31];
#pragma unroll
    for (int rt = 0; rt < 4; ++rt)
#pragma unroll
      for (int g = 0; g < 4; ++g)
#pragma unroll
        for (int e = 0; e < 4; ++e) {
          float a = acc[rt][g * 4 + e] + bias;
          float t = __expf(-a);
          float s = __builtin_amdgcn_rcpf(1.0f + t);
          zbuf[C0 + rt * CH + (e + 8 * g) * 8] = f2bc(wl * s);
        }
  };
  // d = g * s -> zbuf (s from slab, same thread that wrote it)
  auto bwd_epi = [&](const u64* slab) {
#pragma unroll
    for (int rt = 0; rt < 4; ++rt)
#pragma unroll
      for (int g = 0; g < 4; ++g) {
        u64 v = slab[((blk * 16 + w) * 16 + rt * 4 + g) * 64 + lane];
#pragma unroll
        for (int e = 0; e < 4; ++e) {
          float s = b2f((u32)(v >> (16 * e)) & 0xffffu);
          float d = acc[rt][g * 4 + e] * s;
          zbuf[C0 + rt * CH + (e + 8 * g) * 8] = f2bc(d);
        }
      }
  };

  // grad mini-phase: pk += zbuf(d)-tile @ Wg-tile over this wave's K-half.
  // 16 waves = 8 tiles (tr=t&3, tc=t>>2 of the [128x64] grad) x 2 K-halves.
  auto minigrad = [&](const u16* Wg, bool init) {
    int t = w & 7, kh = w >> 3;
    int tr = t & 3, tc = t >> 2;
    const u16* gb = Wg + (tc * 32 + kh * 16) * 512 + lane * 8;
    f32x16 acu = pk;
    if (init) acu = Z16;
#pragma unroll 2
    for (int i = 0; i < 16; ++i) {
      bf16x8 a = ldA(tr, kh * 16 + i);
      bf16x8 g = *(const bf16x8*)(gb + i * 512);
      __builtin_amdgcn_s_setprio(1);
      acu = __builtin_amdgcn_mfma_f32_32x32x16_bf16(a, g, acu, 0, 0, 0);
      __builtin_amdgcn_s_setprio(0);
    }
    pk = acu;
  };

  // ---------------- forward ----------------
  lbar();                                   // xbuf ready
  fwdX(Wz0b);                               // a0 = x@Wz0^T
  fwd_epi(bz0, slab0);                      // z0 -> zbuf (no prior readers)
  lbar();
  fwdX(Wx0b); fwdH(Wz1b);                   // a1 = x@Wx0^T + z0@Wz1^T
  lbar();                                   // z0 reads done
  fwd_epi(bx0, slab1);                      // z1 -> zbuf
  lbar();
  fwdX(Wx1b); fwdH(Wz2b);                   // a2
  lbar();
  fwd_epi(bx1, slab2);                      // z2 -> zbuf
  lbar();
  fwdX(Wx2b); fwdH(Wz3b);                   // a3 (last use of xbuf)
  lbar();
  d3_epi(bx2);                              // d3 -> zbuf
  lbar();
  // ---------------- backward ----------------
  minigrad(Wx2t, true);                     // pk  = d3@Wx2t (wave's slice)
  zeroAcc(); fwdH(Wz3t);                    // acc = d3@Wz3
  lbar();                                   // d3 reads done
  bwd_epi(slab2);                           // d2 -> zbuf
  lbar();
  minigrad(Wx1t, false);                    // pk += d2@Wx1t
  zeroAcc(); fwdH(Wz2t);                    // acc = d2@Wz2
  lbar();
  bwd_epi(slab1);                           // d1 -> zbuf
  lbar();
  minigrad(Wx0t, false);                    // pk += d1@Wx0t
  zeroAcc(); fwdH(Wz1t);                    // acc = d1@Wz1
  lbar();
  bwd_epi(slab0);                           // d0 -> zbuf
  lbar();
  // ---- final: out = d0@Wz0t + pk + WxL; 2-way K-reduce via zbuf park ----
  minigrad(Wz0t, false);                    // pk += d0@Wz0t
  lbar();                                   // all d0 reads done; zbuf dead
  if (w >= 8) {                             // K-half 1 parks its partials
    float* park = (float*)zbuf;             // 8 waves x 16 regs x 64 lanes f32
#pragma unroll
    for (int reg = 0; reg < 16; ++reg)
      park[((w - 8) * 16 + reg) * 64 + lane] = pk[reg];
  }
  lbar();
  if (w < 8) {                              // K-half 0 reduces + stores
    int tr = w & 3, tc = w >> 2;
    int col = tc * 32 + l31;
    float wx = WxL[col];
    const float* park = (const float*)zbuf;
#pragma unroll
    for (int g = 0; g < 4; ++g)
#pragma unroll
      for (int e = 0; e < 4; ++e) {
        int reg = g * 4 + e;
        float v = pk[reg] + park[(w * 16 + reg) * 64 + lane];
        int row = blk * BM + tr * 32 + e + 8 * g + 4 * q5;
        out[row * D + col] = v + wx;
      }
  }
}

extern "C" void kernel_launch(void* const* d_in, const int* in_sizes, int n_in,
                              void* d_out, int out_size, void* d_ws, size_t ws_size,
                              hipStream_t stream) {
  const float* state = (const float*)d_in[0];
  const float* Wz0 = (const float*)d_in[1];
  const float* bz0 = (const float*)d_in[2];
  const float* Wz1 = (const float*)d_in[3];
  const float* Wz2 = (const float*)d_in[4];
  const float* Wz3 = (const float*)d_in[5];
  const float* WzL = (const float*)d_in[6];
  const float* Wx0 = (const float*)d_in[7];
  const float* bx0 = (const float*)d_in[8];
  const float* Wx1 = (const float*)d_in[9];
  const float* bx1 = (const float*)d_in[10];
  const float* Wx2 = (const float*)d_in[11];
  const float* bx2 = (const float*)d_in[12];
  const float* WxL = (const float*)d_in[13];

  if (ws_size < (size_t)WS_ELEMS * 2) {
    fill_sentinel<<<(out_size + 255) / 256, 256, 0, stream>>>((float*)d_out, out_size);
    return;
  }
  u16* wsw = (u16*)d_ws;
  prep_kernel<<<OFF_WEND / 256, 256, 0, stream>>>(Wz0, Wz1, Wz2, Wz3, Wx0, Wx1, Wx2, wsw);
  icnn_kernel<<<B_TOTAL / BM, 1024, 0, stream>>>(state, bz0, bx0, bx1, bx2, WzL, WxL,
                                                 wsw, (float*)d_out);
}

// Round 16
// 416.091 us; speedup vs baseline: 1.0738x; 1.0738x over previous
//
#include <hip/hip_runtime.h>

typedef unsigned short u16;
typedef unsigned int u32;
typedef unsigned long long u64;

#define B_TOTAL 65536
#define H 512
#define D 64
#define BM 64

typedef __bf16 bf16x8 __attribute__((ext_vector_type(8)));
typedef float f32x4 __attribute__((ext_vector_type(4)));

__device__ __forceinline__ u32 f2b(float f) {  // fp32 -> bf16 bits, RNE (sw)
  u32 u = __builtin_bit_cast(u32, f);
  return (u + 0x7fffu + ((u >> 16) & 1u)) >> 16;
}
__device__ __forceinline__ u16 f2bc(float f) { // fp32 -> bf16 bits via HW cvt
  return __builtin_bit_cast(u16, (__bf16)f);   // RNE; compiler pairs into
}                                              // v_cvt_pk_bf16_f32
__device__ __forceinline__ float b2f(u32 bits) {
  return __builtin_bit_cast(float, bits << 16);
}

// ---- workspace layout (bf16 element offsets) ----
// Weight regions are FRAGMENT-PACKED: for logical B-matrix M[NN][KK],
// packed[( (n>>4)*(KK/32) + (k>>5) )*512 + lane*8 + j] = M[n][k],
// n = ntile*16 + (lane&15), k = kstep*32 + (lane>>4)*8 + j.
#define OFF_Wz0b 0          /* [N=512][K=64]  fwd L0 */
#define OFF_Wx0b 32768
#define OFF_Wx1b 65536
#define OFF_Wx2b 98304
#define OFF_Wz1b 131072     /* [N=512][K=512] fwd */
#define OFF_Wz2b 393216
#define OFF_Wz3b 655360
#define OFF_Wz1t 917504     /* [N=512][K=512] transposed, bwd */
#define OFF_Wz2t 1179648
#define OFF_Wz3t 1441792
#define OFF_Wz0t 1703936    /* [N=64][K=512] transposed grad weights */
#define OFF_Wx0t 1736704
#define OFF_Wx1t 1769472
#define OFF_Wx2t 1802240
#define OFF_WEND 1835008
// Slabs deleted in R9 (sigmoids live in registers); workspace is weights only.
#define WS_ELEMS OFF_WEND

// ---- weight prep: fp32 -> bf16, fragment-packed (+ transposed variants) ----
__global__ __launch_bounds__(256) void prep_kernel(
    const float* __restrict__ Wz0, const float* __restrict__ Wz1,
    const float* __restrict__ Wz2, const float* __restrict__ Wz3,
    const float* __restrict__ Wx0, const float* __restrict__ Wx1,
    const float* __restrict__ Wx2, u16* __restrict__ wsb) {
  int i = blockIdx.x * 256 + threadIdx.x;   // grid exactly covers OFF_WEND
  const float* src;
  int NN, KK, trans, p;
  if (i < 131072) {                          // x-path fwd: [512][64] direct
    int r = i >> 15; p = i & 32767;
    src = (r == 0) ? Wz0 : (r == 1) ? Wx0 : (r == 2) ? Wx1 : Wx2;
    NN = 512; KK = 64; trans = 0;
  } else if (i < 917504) {                   // H fwd: [512][512] direct
    int j = i - 131072; int r = j >> 18; p = j & 262143;
    src = (r == 0) ? Wz1 : (r == 1) ? Wz2 : Wz3;
    NN = 512; KK = 512; trans = 0;
  } else if (i < 1703936) {                  // H bwd: transposed
    int j = i - 917504; int r = j >> 18; p = j & 262143;
    src = (r == 0) ? Wz1 : (r == 1) ? Wz2 : Wz3;
    NN = 512; KK = 512; trans = 1;
  } else {                                   // grad weights: [64][512] = W^T
    int j = i - 1703936; int r = j >> 15; p = j & 32767;
    src = (r == 0) ? Wz0 : (r == 1) ? Wx0 : (r == 2) ? Wx1 : Wx2;
    NN = 64; KK = 512; trans = 1;
  }
  int jj = p & 7, lane = (p >> 3) & 63, blk = p >> 9;
  int kt_sh = (KK == 64) ? 1 : 4;            // log2(KK/32)
  int ntile = blk >> kt_sh;
  int kstep = blk & ((1 << kt_sh) - 1);
  int n = ntile * 16 + (lane & 15);
  int k = kstep * 32 + ((lane >> 4) << 3) + jj;
  float v = trans ? src[k * NN + n] : src[n * KK + k];
  wsb[i] = (u16)f2b(v);
}

__global__ __launch_bounds__(256) void fill_sentinel(float* out, int n) {
  int i = blockIdx.x * 256 + threadIdx.x;
  if (i < n) out[i] = 12345.0f;   // unmistakable "workspace too small" marker
}

// ---- fully-fused ICNN fwd+bwd (single GEMM kernel) ----
// ROUND-16 = ROUND-12 (346us, the measured best; R13 BM=32 / R14 32x32 /
// R15 BM=128 all regressed -> R12's geometry is the traffic-balanced point:
// A-LDS 1MB/fwdH ~ B-L2 0.5MB/fwdH ~ balanced walls) + ONE contained fix:
// ZBUF BLOCK SWIZZLE. The epi scatter writes hit only 8/32 banks (for fixed
// (mt,nt,r), lanes land in blocks kq*16+q*4+r -> 8 blocks aliasing 8 banks;
// 9.4e6 conflict-cycles ~ 15us/CU). Permuting the 64 16B-blocks of each 1KB
// chunk by the involution P(b)=b^(b>>3) spreads writes over all 32 banks
// (enumeration: ((q&1)*4+r)^(kq*2+(q>>1)) covers all 8 block residues) while
// reads stay conflict-free (each lane still reads one whole block; P is a
// bijection).
// Carried from R12: B weights stream global->VGPR depth-2 rotation,
// register sigmoids sg0..2, ping-pong K-major zbuf, 8 LDS-only barriers,
// col-split ownership (wave w: cols [w*32,+32), acc[4][2]), HW bf16 cvt,
// minigrad chain-split, setprio. LDS = 2x64K + 9.2K = 137 KB, 16 waves.
__global__ __launch_bounds__(1024, 4) void icnn_kernel(
    const float* __restrict__ state,
    const float* __restrict__ bz0, const float* __restrict__ bx0,
    const float* __restrict__ bx1, const float* __restrict__ bx2,
    const float* __restrict__ WzL, const float* __restrict__ WxL,
    u16* __restrict__ wsw, float* __restrict__ out) {
  __shared__ u16 zbA[BM * H];       // K-major activations, ping  (64 KB)
  __shared__ u16 zbB[BM * H];       // K-major activations, pong  (64 KB)
  __shared__ u16 xbuf[BM * 72];     // padded x staging, 9.2 KB

  const int tid = threadIdx.x;
  const int w = tid >> 6;           // 0..15
  const int lane = tid & 63;
  const int l15 = lane & 15;
  const int q = lane >> 4;
  const int blk = blockIdx.x;
  const int pl8 = (lane ^ (lane >> 3)) * 8;   // swizzled read-block offset

  const u16* Wz0b = wsw + OFF_Wz0b;
  const u16* Wx0b = wsw + OFF_Wx0b;
  const u16* Wx1b = wsw + OFF_Wx1b;
  const u16* Wx2b = wsw + OFF_Wx2b;
  const u16* Wz1b = wsw + OFF_Wz1b;
  const u16* Wz2b = wsw + OFF_Wz2b;
  const u16* Wz3b = wsw + OFF_Wz3b;
  const u16* Wz1t = wsw + OFF_Wz1t;
  const u16* Wz2t = wsw + OFF_Wz2t;
  const u16* Wz3t = wsw + OFF_Wz3t;
  const u16* Wz0t = wsw + OFF_Wz0t;
  const u16* Wx0t = wsw + OFF_Wx0t;
  const u16* Wx1t = wsw + OFF_Wx1t;
  const u16* Wx2t = wsw + OFF_Wx2t;

  // LDS-only barrier: orders zbuf ds ops across waves; global loads/stores
  // stay in flight across it (no vmcnt drain).
  auto lbar = [&]() {
    asm volatile("s_waitcnt lgkmcnt(0)" ::: "memory");
    __builtin_amdgcn_s_barrier();
    asm volatile("" ::: "memory");
  };

  // ---- stage x = state-1 into xbuf (bf16, padded row-major) ----
  {
    int r = tid >> 4, c0 = (tid & 15) << 2;  // 64 rows x 16 chunks of 4 floats
    const float* p = state + (blk * BM + r) * D + c0;
    f32x4 v = __builtin_nontemporal_load((const f32x4*)p);
    u32* dst = (u32*)&xbuf[r * 72 + c0];
    dst[0] = (u32)f2bc(v[0] - 1.0f) | ((u32)f2bc(v[1] - 1.0f) << 16);
    dst[1] = (u32)f2bc(v[2] - 1.0f) | ((u32)f2bc(v[3] - 1.0f) << 16);
  }

  f32x4 acc[4][2];                  // 32 acc regs: 64 rows x 32 cols / wave
  const f32x4 Z = {0.f, 0.f, 0.f, 0.f};
  f32x4 pk = Z;                     // grad park: wave's single 16x16 out tile
  u64 sg0[8], sg1[8], sg2[8];       // register-resident sigmoids, 48 VGPRs

  // zbuf: per (kstep, rowtile) 1KB chunk of 64x 16B blocks; blocks stored
  // permuted by P(b)=b^(b>>3). Reads: lane reads its whole (permuted) block
  // -> conflict-free. Writes: P spreads the epi scatter over all 32 banks.
  auto ldA = [&](const u16* zb, int mt, int step) -> bf16x8 {
    return *(const bf16x8*)(&zb[(step * 4 + mt) * 512 + pl8]);
  };
  auto ldX = [&](int mt, int ks) -> bf16x8 {       // x A-frag from padded xbuf
    return *(const bf16x8*)(&xbuf[(mt * 16 + l15) * 72 + ks * 32 + q * 8]);
  };
  auto wrZ = [&](u16* zb, int row, int n, u16 bits) {  // swizzled scatter
    int b = ((n >> 3) & 3) * 16 + (row & 15);          // logical block
    zb[((n >> 5) * 4 + (row >> 4)) * 512 + (b ^ (b >> 3)) * 8 + (n & 7)] = bits;
  };
  auto zeroAcc = [&]() {
#pragma unroll
    for (int mt = 0; mt < 4; ++mt)
#pragma unroll
      for (int nt = 0; nt < 2; ++nt) acc[mt][nt] = Z;
  };

  // acc = x @ Wx^T (K=64), zero-start. Wx streams global->VGPR.
  auto fwdX = [&](const u16* Wxp) {
    const u16* xb = Wxp + lane * 8;
#pragma unroll
    for (int ks = 0; ks < 2; ++ks) {
      bf16x8 b2[2];
#pragma unroll
      for (int nt = 0; nt < 2; ++nt)
        b2[nt] = *(const bf16x8*)(xb + ((w * 2 + nt) * 2 + ks) * 512);
#pragma unroll
      for (int mt = 0; mt < 4; ++mt) {
        bf16x8 ax = ldX(mt, ks);
#pragma unroll
        for (int nt = 0; nt < 2; ++nt) {
          f32x4 c = (ks == 0) ? Z : acc[mt][nt];
          acc[mt][nt] = __builtin_amdgcn_mfma_f32_16x16x32_bf16(ax, b2[nt], c, 0, 0, 0);
        }
      }
    }
  };

  // acc += zb @ W^T (K=512), ALWAYS accumulating (callers zeroAcc first
  // if needed). B streams global->VGPR with DEPTH-2 rotation: the frags
  // consumed at step st were loaded at st-2 (>=2 contended iterations of
  // wall time) so the L2 ~200cy latency is covered. unroll 2 lets regalloc
  // rename the 2-level rotation away.
  auto fwdH = [&](const u16* Wp, const u16* zb) {
    const u16* gb = Wp + (w * 2 * 16) * 512 + lane * 8;
    bf16x8 b00 = *(const bf16x8*)(gb);                 // st+0
    bf16x8 b01 = *(const bf16x8*)(gb + 16 * 512);
    bf16x8 b10 = *(const bf16x8*)(gb + 512);           // st+1
    bf16x8 b11 = *(const bf16x8*)(gb + 17 * 512);
#pragma unroll 2
    for (int st = 0; st < 16; ++st) {
      int stp = (st < 14) ? st + 2 : st;   // prefetch st+2 (clamped re-read)
      bf16x8 bn0 = *(const bf16x8*)(gb + stp * 512);
      bf16x8 bn1 = *(const bf16x8*)(gb + (16 + stp) * 512);
      bf16x8 a[4];
#pragma unroll
      for (int mt = 0; mt < 4; ++mt) a[mt] = ldA(zb, mt, st);
      __builtin_amdgcn_s_setprio(1);
#pragma unroll
      for (int mt = 0; mt < 4; ++mt)
        acc[mt][0] = __builtin_amdgcn_mfma_f32_16x16x32_bf16(
            a[mt], b00, acc[mt][0], 0, 0, 0);
#pragma unroll
      for (int mt = 0; mt < 4; ++mt)
        acc[mt][1] = __builtin_amdgcn_mfma_f32_16x16x32_bf16(
            a[mt], b01, acc[mt][1], 0, 0, 0);
      __builtin_amdgcn_s_setprio(0);
      b00 = b10; b01 = b11; b10 = bn0; b11 = bn1;
    }
  };

  // forward epilogue: a+=bias; z=softplus -> zb; s=sigmoid -> sg (registers)
  auto fwd_epi = [&](const float* biasp, u64 (&sg)[8], u16* zb) {
    float bias[2];
#pragma unroll
    for (int nt = 0; nt < 2; ++nt) bias[nt] = biasp[(w * 2 + nt) * 16 + l15];
#pragma unroll
    for (int mt = 0; mt < 4; ++mt)
#pragma unroll
      for (int nt = 0; nt < 2; ++nt) {
        int n = (w * 2 + nt) * 16 + l15;
        f32x4 A = acc[mt][nt];
        u64 pack = 0;
#pragma unroll
        for (int r = 0; r < 4; ++r) {
          float a = A[r] + bias[nt];
          float t = __expf(-a);
          float u = 1.0f + t;
          float s = __builtin_amdgcn_rcpf(u);     // sigmoid(a)
          float z = a + __logf(u);                // softplus(a)
          pack |= (u64)f2bc(s) << (16 * r);
          wrZ(zb, mt * 16 + q * 4 + r, n, f2bc(z));
        }
        sg[mt * 2 + nt] = pack;                   // static index (full unroll)
      }
  };
  auto d3_epi = [&](const float* biasp, u16* zb) {  // d3 = WzL*sigmoid(a3)
    float bias[2], wl[2];
#pragma unroll
    for (int nt = 0; nt < 2; ++nt) {
      bias[nt] = biasp[(w * 2 + nt) * 16 + l15];
      wl[nt] = WzL[(w * 2 + nt) * 16 + l15];
    }
#pragma unroll
    for (int mt = 0; mt < 4; ++mt)
#pragma unroll
      for (int nt = 0; nt < 2; ++nt) {
        int n = (w * 2 + nt) * 16 + l15;
        f32x4 A = acc[mt][nt];
#pragma unroll
        for (int r = 0; r < 4; ++r) {
          float a = A[r] + bias[nt];
          float t = __expf(-a);
          float s = __builtin_amdgcn_rcpf(1.0f + t);
          wrZ(zb, mt * 16 + q * 4 + r, n, f2bc(wl[nt] * s));
        }
      }
  };
  // d = g * s -> zb (s from registers; same thread produced both)
  auto bwd_epi = [&](const u64 (&sg)[8], u16* zb) {
#pragma unroll
    for (int mt = 0; mt < 4; ++mt)
#pragma unroll
      for (int nt = 0; nt < 2; ++nt) {
        int n = (w * 2 + nt) * 16 + l15;
        f32x4 A = acc[mt][nt];
        u64 v = sg[mt * 2 + nt];                  // static index
#pragma unroll
        for (int r = 0; r < 4; ++r) {
          float s = b2f((u32)(v >> (16 * r)) & 0xffffu);
          wrZ(zb, mt * 16 + q * 4 + r, n, f2bc(A[r] * s));
        }
      }
  };

  // grad mini-phase: pk += zb(d) @ Wg (main acc is DEAD here).
  // 16 waves <-> 16 out tiles: wave w owns tile (rt=w&3, ct=w>>2).
  // Chain split even/odd: two 8-deep independent MFMA chains instead of
  // one 16-deep dependent chain (latency, not throughput, bound before).
  auto minigrad = [&](const u16* Wg, const u16* zb, bool init) {
    int rt = w & 3, ct = w >> 2;
    const u16* gb = Wg + lane * 8;
    f32x4 ta = init ? Z : pk, tb = Z;
#pragma unroll 2
    for (int st = 0; st < 16; st += 2) {
      bf16x8 a0 = ldA(zb, rt, st);
      bf16x8 g0 = *(const bf16x8*)(gb + (ct * 16 + st) * 512);
      bf16x8 a1 = ldA(zb, rt, st + 1);
      bf16x8 g1 = *(const bf16x8*)(gb + (ct * 16 + st + 1) * 512);
      __builtin_amdgcn_s_setprio(1);
      ta = __builtin_amdgcn_mfma_f32_16x16x32_bf16(a0, g0, ta, 0, 0, 0);
      tb = __builtin_amdgcn_mfma_f32_16x16x32_bf16(a1, g1, tb, 0, 0, 0);
      __builtin_amdgcn_s_setprio(0);
    }
    pk = ta + tb;
  };

  // ---------------- forward ----------------
  lbar();                                   // xbuf ready
  fwdX(Wz0b);                               // a0 = x@Wz0^T
  fwd_epi(bz0, sg0, zbA);                   // z0 -> zbA, s0 -> regs
  lbar();                                   // P0
  fwdX(Wx0b); fwdH(Wz1b, zbA);              // a1 = x@Wx0^T + z0@Wz1^T
  fwd_epi(bx0, sg1, zbB);                   // z1 -> zbB (zbA still readable)
  lbar();                                   // P1
  fwdX(Wx1b); fwdH(Wz2b, zbB);              // a2
  fwd_epi(bx1, sg2, zbA);                   // z2 -> zbA
  lbar();                                   // P2
  fwdX(Wx2b); fwdH(Wz3b, zbA);              // a3
  d3_epi(bx2, zbB);                         // d3 -> zbB
  lbar();                                   // P3
  // ---------------- backward ----------------
  minigrad(Wx2t, zbB, true);                // pk  = d3@Wx2t
  zeroAcc(); fwdH(Wz3t, zbB);               // acc = d3@Wz3
  bwd_epi(sg2, zbA);                        // d2 -> zbA
  lbar();                                   // P4
  minigrad(Wx1t, zbA, false);               // pk += d2@Wx1t
  zeroAcc(); fwdH(Wz2t, zbA);               // acc = d2@Wz2
  bwd_epi(sg1, zbB);                        // d1 -> zbB
  lbar();                                   // P5
  minigrad(Wx0t, zbB, false);               // pk += d1@Wx0t
  zeroAcc(); fwdH(Wz1t, zbB);               // acc = d1@Wz1
  bwd_epi(sg0, zbA);                        // d0 -> zbA
  lbar();                                   // P6
  // ---- final: out = d0@Wz0t + pk + WxL ----
  minigrad(Wz0t, zbA, false);               // pk += d0@Wz0t
  {
    int rt = w & 3, ct = w >> 2;
    float wx = WxL[ct * 16 + l15];
#pragma unroll
    for (int r = 0; r < 4; ++r) {
      int row = blk * BM + rt * 16 + q * 4 + r;
      out[row * D + ct * 16 + l15] = pk[r] + wx;
    }
  }
}

extern "C" void kernel_launch(void* const* d_in, const int* in_sizes, int n_in,
                              void* d_out, int out_size, void* d_ws, size_t ws_size,
                              hipStream_t stream) {
  const float* state = (const float*)d_in[0];
  const float* Wz0 = (const float*)d_in[1];
  const float* bz0 = (const float*)d_in[2];
  const float* Wz1 = (const float*)d_in[3];
  const float* Wz2 = (const float*)d_in[4];
  const float* Wz3 = (const float*)d_in[5];
  const float* WzL = (const float*)d_in[6];
  const float* Wx0 = (const float*)d_in[7];
  const float* bx0 = (const float*)d_in[8];
  const float* Wx1 = (const float*)d_in[9];
  const float* bx1 = (const float*)d_in[10];
  const float* Wx2 = (const float*)d_in[11];
  const float* bx2 = (const float*)d_in[12];
  const float* WxL = (const float*)d_in[13];

  if (ws_size < (size_t)WS_ELEMS * 2) {
    fill_sentinel<<<(out_size + 255) / 256, 256, 0, stream>>>((float*)d_out, out_size);
    return;
  }
  u16* wsw = (u16*)d_ws;
  prep_kernel<<<OFF_WEND / 256, 256, 0, stream>>>(Wz0, Wz1, Wz2, Wz3, Wx0, Wx1, Wx2, wsw);
  icnn_kernel<<<B_TOTAL / BM, 1024, 0, stream>>>(state, bz0, bx0, bx1, bx2, WzL, WxL,
                                                 wsw, (float*)d_out);
}